// Round 5
// baseline (482.103 us; speedup 1.0000x reference)
//
#include <hip/hip_runtime.h>
#include <hip/hip_cooperative_groups.h>
#include <math.h>

namespace cg = cooperative_groups;

#define EPS 1e-5f

typedef __attribute__((ext_vector_type(8)))  _Float16 half8;   // 8 f16 (4 VGPR)
typedef __attribute__((ext_vector_type(16))) float    floatx16;

__device__ __forceinline__ unsigned short f2h_bits(float f) {
    _Float16 h = (_Float16)f;
    return __builtin_bit_cast(unsigned short, h);
}

// ===========================================================================
// FUSED COOPERATIVE KERNEL (round 5): pack -> sync -> deconv+stats -> sync ->
// GN finalize+apply. 512 persistent blocks (= today's 2 blocks/CU LDS-capped
// co-residency), grid-stride everywhere. Wins vs 3 dispatches: 2 fewer launch
// gaps; BW staged once per block (29 MB vs 134 MB of L2 reads); stats flushed
// once per block (~5x fewer global atomics); phase-2 reads its own hraw /
// batch_id while still hot in the local XCD L2.
// Deconv core is the round-0-proven structure (unchanged): wave = 32 nodes x
// 32 couts, 32x32x16 f16 MFMA chain, gathers software-pipelined 1 quad ahead.
// ===========================================================================
__global__ __launch_bounds__(256) void fused_all_kernel(
    const float* __restrict__ data, const float* __restrict__ W,
    const int* __restrict__ neigh, const int* __restrict__ batch_id,
    const float* __restrict__ gamma, const float* __restrict__ beta,
    unsigned short* __restrict__ dpk, unsigned short* __restrict__ wpk,
    unsigned short* __restrict__ hraw, int hok,
    float* __restrict__ out,
    float* __restrict__ gs1, float* __restrict__ gs2, float* __restrict__ gcnt,
    int N)
{
    cg::grid_group grid = cg::this_grid();

    __shared__ unsigned short BW[28 * 2 * 64 * 8];    // 57344 B
    __shared__ float ls1[256];
    __shared__ float ls2[256];
    __shared__ float lcnt[8];

    const int t  = threadIdx.x;
    const int nb = gridDim.x;

    // ---------------- phase 0: pack data + weights, zero stats -------------
    for (int i = blockIdx.x * 256 + t; i < N * 8; i += nb * 256) {
        const float4 v = ((const float4*)data)[i];
        ushort4 o;
        o.x = f2h_bits(v.x);
        o.y = f2h_bits(v.y);
        o.z = f2h_bits(v.z);
        o.w = f2h_bits(v.w);
        ((ushort4*)dpk)[i] = o;
    }
    for (int i = blockIdx.x * 256 + t; i < 28 * 2 * 64; i += nb * 256) {
        const int l = i & 63;
        const int c = (i >> 6) & 1;
        const int k = i >> 7;
        ushort4 o0 = make_ushort4(0, 0, 0, 0), o1 = o0;
        if (k < 27) {
            const int n  = l & 31;
            const int cb = c * 16 + (l >> 5) * 8;    // ci base for this lane
            const float* wp = W + k * 1024 + n;
            o0.x = f2h_bits(wp[(cb + 0) * 32]);
            o0.y = f2h_bits(wp[(cb + 1) * 32]);
            o0.z = f2h_bits(wp[(cb + 2) * 32]);
            o0.w = f2h_bits(wp[(cb + 3) * 32]);
            o1.x = f2h_bits(wp[(cb + 4) * 32]);
            o1.y = f2h_bits(wp[(cb + 5) * 32]);
            o1.z = f2h_bits(wp[(cb + 6) * 32]);
            o1.w = f2h_bits(wp[(cb + 7) * 32]);
        }
        *(ushort4*)(wpk + (size_t)i * 8)     = o0;
        *(ushort4*)(wpk + (size_t)i * 8 + 4) = o1;
    }
    if (blockIdx.x == nb - 1 && t < 520) gs1[t] = 0.f;  // gs1|gs2|gcnt contiguous

    __threadfence();
    grid.sync();

    // ---------------- phase 1: deconv + stats ------------------------------
    // stage all B fragments to LDS ONCE per persistent block
#pragma unroll
    for (int r = 0; r < 14; ++r)
        ((int4*)BW)[r * 256 + t] = ((const int4*)wpk)[r * 256 + t];
    ls1[t] = 0.f;
    ls2[t] = 0.f;
    if (t < 8) lcnt[t] = 0.f;
    __syncthreads();

    const int wv   = t >> 6;
    const int l    = t & 63;
    const int mrow = l & 31;
    const int half = l >> 5;
    const int aoff = half * 8;       // f16 offset: chunk c base = 16c + 8*half
    const half8* BL = (const half8*)BW;

    const int nchunks = (N + 127) / 128;
    for (int ch = blockIdx.x; ch < nchunks; ch += nb) {
        const int wbase = ch * 128 + wv * 32;
        const int node  = wbase + mrow;
        const int nc    = node < N ? node : N - 1;

        floatx16 acc;
#pragma unroll
        for (int r = 0; r < 16; ++r) acc[r] = 0.f;

        const int* nrow = neigh + (size_t)nc * 27;

        int4 nq;
        nq.x = nrow[0]; nq.y = nrow[1]; nq.z = nrow[2]; nq.w = nrow[3];

        half8 a0, a1, a2, a3, a4, a5, a6, a7;   // quad: tap j, chunk c -> a(2j+c)
        {
            const unsigned short* r0 = dpk + (size_t)nq.x * 32;
            const unsigned short* r1 = dpk + (size_t)nq.y * 32;
            const unsigned short* r2 = dpk + (size_t)nq.z * 32;
            const unsigned short* r3 = dpk + (size_t)nq.w * 32;
            a0 = *(const half8*)(r0 + aoff);  a1 = *(const half8*)(r0 + 16 + aoff);
            a2 = *(const half8*)(r1 + aoff);  a3 = *(const half8*)(r1 + 16 + aoff);
            a4 = *(const half8*)(r2 + aoff);  a5 = *(const half8*)(r2 + 16 + aoff);
            a6 = *(const half8*)(r3 + aoff);  a7 = *(const half8*)(r3 + 16 + aoff);
        }

#pragma unroll 1
        for (int it = 0; it < 7; ++it) {
            half8 b0, b1, b2, b3, b4, b5, b6, b7;
            if (it < 6) {            // issue next quad's gathers (latency cover)
                const int kb = (it + 1) * 4;
                int4 nqn;
                nqn.x = nrow[kb];
                nqn.y = nrow[kb + 1];
                nqn.z = nrow[kb + 2];
                nqn.w = nrow[kb + 3 < 27 ? kb + 3 : 26];
                const unsigned short* r0 = dpk + (size_t)nqn.x * 32;
                const unsigned short* r1 = dpk + (size_t)nqn.y * 32;
                const unsigned short* r2 = dpk + (size_t)nqn.z * 32;
                const unsigned short* r3 = dpk + (size_t)nqn.w * 32;
                b0 = *(const half8*)(r0 + aoff);  b1 = *(const half8*)(r0 + 16 + aoff);
                b2 = *(const half8*)(r1 + aoff);  b3 = *(const half8*)(r1 + 16 + aoff);
                b4 = *(const half8*)(r2 + aoff);  b5 = *(const half8*)(r2 + 16 + aoff);
                b6 = *(const half8*)(r3 + aoff);  b7 = *(const half8*)(r3 + 16 + aoff);
            }

            acc = __builtin_amdgcn_mfma_f32_32x32x16_f16(a0, BL[(8 * it + 0) * 64 + l], acc, 0, 0, 0);
            acc = __builtin_amdgcn_mfma_f32_32x32x16_f16(a1, BL[(8 * it + 1) * 64 + l], acc, 0, 0, 0);
            acc = __builtin_amdgcn_mfma_f32_32x32x16_f16(a2, BL[(8 * it + 2) * 64 + l], acc, 0, 0, 0);
            acc = __builtin_amdgcn_mfma_f32_32x32x16_f16(a3, BL[(8 * it + 3) * 64 + l], acc, 0, 0, 0);
            acc = __builtin_amdgcn_mfma_f32_32x32x16_f16(a4, BL[(8 * it + 4) * 64 + l], acc, 0, 0, 0);
            acc = __builtin_amdgcn_mfma_f32_32x32x16_f16(a5, BL[(8 * it + 5) * 64 + l], acc, 0, 0, 0);
            acc = __builtin_amdgcn_mfma_f32_32x32x16_f16(a6, BL[(8 * it + 6) * 64 + l], acc, 0, 0, 0);
            acc = __builtin_amdgcn_mfma_f32_32x32x16_f16(a7, BL[(8 * it + 7) * 64 + l], acc, 0, 0, 0);

            if (it < 6) {
                a0 = b0; a1 = b1; a2 = b2; a3 = b3;
                a4 = b4; a5 = b5; a6 = b6; a7 = b7;
            }
        }

        // ---- epilogue: C layout col=l&31, row=(r&3)+8(r>>2)+4*half
        const int co = mrow;
        if (hok) {
#pragma unroll
            for (int r = 0; r < 16; ++r) {
                const int row = (r & 3) + 8 * (r >> 2) + 4 * half;
                const int n = wbase + row;
                if (n < N) hraw[(size_t)n * 32 + co] = f2h_bits(acc[r]);
            }
        } else {
#pragma unroll
            for (int r = 0; r < 16; ++r) {
                const int row = (r & 3) + 8 * (r >> 2) + 4 * half;
                const int n = wbase + row;
                if (n < N) out[(size_t)n * 32 + co] = acc[r];
            }
        }

        bool fast = (wbase + 31 < N);
        int bfst = 0;
        if (fast) {
            bfst = batch_id[wbase];
            fast = (bfst == batch_id[wbase + 31]);
        }
        if (fast) {
            float s1 = 0.f, s2 = 0.f;
#pragma unroll
            for (int r = 0; r < 16; ++r) {
                const float v = acc[r];
                s1 += v;
                s2 += v * v;
            }
            atomicAdd(&ls1[bfst * 32 + co], s1);
            atomicAdd(&ls2[bfst * 32 + co], s2);
        } else {
#pragma unroll
            for (int r = 0; r < 16; ++r) {
                const int row = (r & 3) + 8 * (r >> 2) + 4 * half;
                const int n = wbase + row;
                if (n < N) {
                    const int b = batch_id[n];
                    const float v = acc[r];
                    atomicAdd(&ls1[b * 32 + co], v);
                    atomicAdd(&ls2[b * 32 + co], v * v);
                }
            }
        }
        if (half == 0) {
            const int n = wbase + mrow;
            if (n < N) atomicAdd(&lcnt[batch_id[n]], 1.0f);
        }
    }

    __syncthreads();
    {   // flush block-local stats ONCE per persistent block
        float v;
        v = ls1[t]; if (v != 0.f) atomicAdd(&gs1[t], v);
        v = ls2[t]; if (v != 0.f) atomicAdd(&gs2[t], v);
        if (t < 8) { v = lcnt[t]; if (v != 0.f) atomicAdd(&gcnt[t], v); }
    }

    __threadfence();
    grid.sync();

    // ---------------- phase 2: GN finalize + apply + ReLU ------------------
    for (int idx = blockIdx.x * 256 + t; idx < N * 8; idx += nb * 256) {
        const int n = idx >> 3;
        const int g = idx & 7;
        const int b = batch_id[n];

        const float cnt  = gcnt[b] * 4.0f;
        const float icnt = 1.0f / (cnt + EPS);
        const float4 s1 = *(const float4*)(gs1 + b * 32 + g * 4);
        const float4 s2 = *(const float4*)(gs2 + b * 32 + g * 4);
        const float S1 = s1.x + s1.y + s1.z + s1.w;
        const float S2 = s2.x + s2.y + s2.z + s2.w;
        const float m   = S1 * icnt;
        const float var = (S2 - 2.0f * m * S1 + cnt * m * m) * icnt;
        const float istd = rsqrtf(var + EPS);

        const float4 gm4 = *(const float4*)(gamma + g * 4);
        const float4 bt4 = *(const float4*)(beta + g * 4);
        float4 h;
        if (hok) {
            const ushort4 hv = *(const ushort4*)(hraw + (size_t)idx * 4);
            h.x = (float)__builtin_bit_cast(_Float16, hv.x);
            h.y = (float)__builtin_bit_cast(_Float16, hv.y);
            h.z = (float)__builtin_bit_cast(_Float16, hv.z);
            h.w = (float)__builtin_bit_cast(_Float16, hv.w);
        } else {
            h = *(float4*)(out + (size_t)idx * 4);
        }
        h.x = fmaxf((h.x - m) * istd * gm4.x + bt4.x, 0.f);
        h.y = fmaxf((h.y - m) * istd * gm4.y + bt4.y, 0.f);
        h.z = fmaxf((h.z - m) * istd * gm4.z + bt4.z, 0.f);
        h.w = fmaxf((h.w - m) * istd * gm4.w + bt4.w, 0.f);
        *(float4*)(out + (size_t)idx * 4) = h;
    }
}

// ===========================================================================
// FALLBACK PATH: round-4 proven 3-dispatch pipeline (260.2 us), used when the
// cooperative launch is unavailable.
// ===========================================================================
__global__ __launch_bounds__(256) void pack_all_kernel(
    const float* __restrict__ data, unsigned short* __restrict__ dpk,
    const float* __restrict__ W, unsigned short* __restrict__ wpk,
    float* __restrict__ gzero, int N, int nbData)
{
    const int b = blockIdx.x;
    const int tid = threadIdx.x;

    if (b < nbData) {
        const int i = b * 256 + tid;                 // float4 index
        if (i >= N * 8) return;
        const float4 v = ((const float4*)data)[i];
        ushort4 o;
        o.x = f2h_bits(v.x);
        o.y = f2h_bits(v.y);
        o.z = f2h_bits(v.z);
        o.w = f2h_bits(v.w);
        ((ushort4*)dpk)[i] = o;
        return;
    }
    const int wb = b - nbData;
    if (wb < 14) {
        const int t = wb * 256 + tid;                // (tap*2+chunk)*64+lane
        const int l = t & 63;
        const int c = (t >> 6) & 1;
        const int k = t >> 7;
        ushort4 o0 = make_ushort4(0, 0, 0, 0), o1 = o0;
        if (k < 27) {
            const int n  = l & 31;
            const int cb = c * 16 + (l >> 5) * 8;
            const float* wp = W + k * 1024 + n;
            o0.x = f2h_bits(wp[(cb + 0) * 32]);
            o0.y = f2h_bits(wp[(cb + 1) * 32]);
            o0.z = f2h_bits(wp[(cb + 2) * 32]);
            o0.w = f2h_bits(wp[(cb + 3) * 32]);
            o1.x = f2h_bits(wp[(cb + 4) * 32]);
            o1.y = f2h_bits(wp[(cb + 5) * 32]);
            o1.z = f2h_bits(wp[(cb + 6) * 32]);
            o1.w = f2h_bits(wp[(cb + 7) * 32]);
        }
        *(ushort4*)(wpk + (size_t)t * 8)     = o0;
        *(ushort4*)(wpk + (size_t)t * 8 + 4) = o1;
        return;
    }
    if (wb == 14) {
        if (tid < 520) gzero[tid] = 0.f;
        return;
    }
}

__global__ __launch_bounds__(256) void deconv_stats_kernel(
    const unsigned short* __restrict__ dpk, const unsigned short* __restrict__ wpk,
    const int* __restrict__ neigh,
    const int* __restrict__ batch_id, float* __restrict__ out,
    unsigned short* __restrict__ hraw, int hok,
    float* __restrict__ gs1, float* __restrict__ gs2, float* __restrict__ gcnt,
    int N)
{
    __shared__ unsigned short BW[28 * 2 * 64 * 8];    // 57344 B
    __shared__ float ls1[256];
    __shared__ float ls2[256];
    __shared__ float lcnt[8];

    const int t    = threadIdx.x;
    const int wv   = t >> 6;
    const int l    = t & 63;
    const int mrow = l & 31;
    const int half = l >> 5;
    const int wbase = blockIdx.x * 128 + wv * 32;
    const int node  = wbase + mrow;
    const int nc    = node < N ? node : N - 1;

#pragma unroll
    for (int r = 0; r < 14; ++r)
        ((int4*)BW)[r * 256 + t] = ((const int4*)wpk)[r * 256 + t];
    ls1[t] = 0.f;
    ls2[t] = 0.f;
    if (t < 8) lcnt[t] = 0.f;
    __syncthreads();

    floatx16 acc;
#pragma unroll
    for (int r = 0; r < 16; ++r) acc[r] = 0.f;

    const int* nrow = neigh + (size_t)nc * 27;
    const int aoff  = half * 8;

    int4 nq;
    nq.x = nrow[0]; nq.y = nrow[1]; nq.z = nrow[2]; nq.w = nrow[3];

    half8 a0, a1, a2, a3, a4, a5, a6, a7;
    {
        const unsigned short* r0 = dpk + (size_t)nq.x * 32;
        const unsigned short* r1 = dpk + (size_t)nq.y * 32;
        const unsigned short* r2 = dpk + (size_t)nq.z * 32;
        const unsigned short* r3 = dpk + (size_t)nq.w * 32;
        a0 = *(const half8*)(r0 + aoff);  a1 = *(const half8*)(r0 + 16 + aoff);
        a2 = *(const half8*)(r1 + aoff);  a3 = *(const half8*)(r1 + 16 + aoff);
        a4 = *(const half8*)(r2 + aoff);  a5 = *(const half8*)(r2 + 16 + aoff);
        a6 = *(const half8*)(r3 + aoff);  a7 = *(const half8*)(r3 + 16 + aoff);
    }

    const half8* BL = (const half8*)BW;

#pragma unroll 1
    for (int it = 0; it < 7; ++it) {
        half8 b0, b1, b2, b3, b4, b5, b6, b7;
        if (it < 6) {
            const int kb = (it + 1) * 4;
            int4 nqn;
            nqn.x = nrow[kb];
            nqn.y = nrow[kb + 1];
            nqn.z = nrow[kb + 2];
            nqn.w = nrow[kb + 3 < 27 ? kb + 3 : 26];
            const unsigned short* r0 = dpk + (size_t)nqn.x * 32;
            const unsigned short* r1 = dpk + (size_t)nqn.y * 32;
            const unsigned short* r2 = dpk + (size_t)nqn.z * 32;
            const unsigned short* r3 = dpk + (size_t)nqn.w * 32;
            b0 = *(const half8*)(r0 + aoff);  b1 = *(const half8*)(r0 + 16 + aoff);
            b2 = *(const half8*)(r1 + aoff);  b3 = *(const half8*)(r1 + 16 + aoff);
            b4 = *(const half8*)(r2 + aoff);  b5 = *(const half8*)(r2 + 16 + aoff);
            b6 = *(const half8*)(r3 + aoff);  b7 = *(const half8*)(r3 + 16 + aoff);
        }

        acc = __builtin_amdgcn_mfma_f32_32x32x16_f16(a0, BL[(8 * it + 0) * 64 + l], acc, 0, 0, 0);
        acc = __builtin_amdgcn_mfma_f32_32x32x16_f16(a1, BL[(8 * it + 1) * 64 + l], acc, 0, 0, 0);
        acc = __builtin_amdgcn_mfma_f32_32x32x16_f16(a2, BL[(8 * it + 2) * 64 + l], acc, 0, 0, 0);
        acc = __builtin_amdgcn_mfma_f32_32x32x16_f16(a3, BL[(8 * it + 3) * 64 + l], acc, 0, 0, 0);
        acc = __builtin_amdgcn_mfma_f32_32x32x16_f16(a4, BL[(8 * it + 4) * 64 + l], acc, 0, 0, 0);
        acc = __builtin_amdgcn_mfma_f32_32x32x16_f16(a5, BL[(8 * it + 5) * 64 + l], acc, 0, 0, 0);
        acc = __builtin_amdgcn_mfma_f32_32x32x16_f16(a6, BL[(8 * it + 6) * 64 + l], acc, 0, 0, 0);
        acc = __builtin_amdgcn_mfma_f32_32x32x16_f16(a7, BL[(8 * it + 7) * 64 + l], acc, 0, 0, 0);

        if (it < 6) {
            a0 = b0; a1 = b1; a2 = b2; a3 = b3;
            a4 = b4; a5 = b5; a6 = b6; a7 = b7;
        }
    }

    const int co = mrow;
    if (hok) {
#pragma unroll
        for (int r = 0; r < 16; ++r) {
            const int row = (r & 3) + 8 * (r >> 2) + 4 * half;
            const int n = wbase + row;
            if (n < N) hraw[(size_t)n * 32 + co] = f2h_bits(acc[r]);
        }
    } else {
#pragma unroll
        for (int r = 0; r < 16; ++r) {
            const int row = (r & 3) + 8 * (r >> 2) + 4 * half;
            const int n = wbase + row;
            if (n < N) out[(size_t)n * 32 + co] = acc[r];
        }
    }

    bool fast = (wbase + 31 < N);
    int bfst = 0;
    if (fast) {
        bfst = batch_id[wbase];
        fast = (bfst == batch_id[wbase + 31]);
    }
    if (fast) {
        float s1 = 0.f, s2 = 0.f;
#pragma unroll
        for (int r = 0; r < 16; ++r) {
            const float v = acc[r];
            s1 += v;
            s2 += v * v;
        }
        atomicAdd(&ls1[bfst * 32 + co], s1);
        atomicAdd(&ls2[bfst * 32 + co], s2);
    } else {
#pragma unroll
        for (int r = 0; r < 16; ++r) {
            const int row = (r & 3) + 8 * (r >> 2) + 4 * half;
            const int n = wbase + row;
            if (n < N) {
                const int b = batch_id[n];
                const float v = acc[r];
                atomicAdd(&ls1[b * 32 + co], v);
                atomicAdd(&ls2[b * 32 + co], v * v);
            }
        }
    }
    if (half == 0) {
        const int n = wbase + mrow;
        if (n < N) atomicAdd(&lcnt[batch_id[n]], 1.0f);
    }
    __syncthreads();

    {
        float v;
        v = ls1[t]; if (v != 0.f) atomicAdd(&gs1[t], v);
        v = ls2[t]; if (v != 0.f) atomicAdd(&gs2[t], v);
        if (t < 8) { v = lcnt[t]; if (v != 0.f) atomicAdd(&gcnt[t], v); }
    }
}

__global__ __launch_bounds__(256) void gn_relu_kernel(
    float* __restrict__ out, const unsigned short* __restrict__ hraw, int hok,
    const int* __restrict__ batch_id,
    const float* __restrict__ gs1, const float* __restrict__ gs2,
    const float* __restrict__ gcnt, const float* __restrict__ gamma,
    const float* __restrict__ beta, int N)
{
    const int idx = blockIdx.x * 256 + threadIdx.x;
    if (idx >= N * 8) return;
    const int n = idx >> 3;
    const int g = idx & 7;
    const int b = batch_id[n];

    const float cnt  = gcnt[b] * 4.0f;
    const float icnt = 1.0f / (cnt + EPS);
    const float4 s1 = *(const float4*)(gs1 + b * 32 + g * 4);
    const float4 s2 = *(const float4*)(gs2 + b * 32 + g * 4);
    const float S1 = s1.x + s1.y + s1.z + s1.w;
    const float S2 = s2.x + s2.y + s2.z + s2.w;
    const float m   = S1 * icnt;
    const float var = (S2 - 2.0f * m * S1 + cnt * m * m) * icnt;
    const float istd = rsqrtf(var + EPS);

    const float4 gm4 = *(const float4*)(gamma + g * 4);
    const float4 bt4 = *(const float4*)(beta + g * 4);
    float4 h;
    if (hok) {
        const ushort4 hv = *(const ushort4*)(hraw + (size_t)idx * 4);
        h.x = (float)__builtin_bit_cast(_Float16, hv.x);
        h.y = (float)__builtin_bit_cast(_Float16, hv.y);
        h.z = (float)__builtin_bit_cast(_Float16, hv.z);
        h.w = (float)__builtin_bit_cast(_Float16, hv.w);
    } else {
        h = *(float4*)(out + (size_t)idx * 4);
    }
    h.x = fmaxf((h.x - m) * istd * gm4.x + bt4.x, 0.f);
    h.y = fmaxf((h.y - m) * istd * gm4.y + bt4.y, 0.f);
    h.z = fmaxf((h.z - m) * istd * gm4.z + bt4.z, 0.f);
    h.w = fmaxf((h.w - m) * istd * gm4.w + bt4.w, 0.f);
    *(float4*)(out + (size_t)idx * 4) = h;
}

// ---------------------------------------------------------------------------
extern "C" void kernel_launch(void* const* d_in, const int* in_sizes, int n_in,
                              void* d_out, int out_size, void* d_ws, size_t ws_size,
                              hipStream_t stream) {
    const float* data     = (const float*)d_in[0];   // [N,32]
    const float* weights  = (const float*)d_in[1];   // [27,32,32]
    const float* gamma    = (const float*)d_in[2];   // [32]
    const float* beta     = (const float*)d_in[3];   // [32]
    const int*   neigh    = (const int*)d_in[4];     // [N,27]
    const int*   batch_id = (const int*)d_in[5];     // [N]
    const int N = in_sizes[0] / 32;
    float* out = (float*)d_out;

    // ws layout (bytes):
    //   [0, 2080)                 : gs1[256] gs2[256] gcnt[8]
    //   [4096, +N*64)             : dpk   (N x 32 f16)
    //   [.., +57344)              : wpk   (28*2*64 half8 fragments)
    //   [.., +N*64)               : hraw  (N x 32 f16)    -- if ws fits
    char* wsb = (char*)d_ws;
    float* gs1  = (float*)wsb;
    float* gs2  = gs1 + 256;
    float* gcnt = gs1 + 512;
    unsigned short* dpk = (unsigned short*)(wsb + 4096);
    unsigned short* wpk = (unsigned short*)(wsb + 4096 + (size_t)N * 64);
    unsigned short* hraw = (unsigned short*)(wsb + 4096 + (size_t)N * 64 + 57344);

    const size_t need_hr = 4096 + (size_t)N * 64 + 57344 + (size_t)N * 64;
    int hok = (ws_size >= need_hr) ? 1 : 0;

    // ---- try single cooperative fused launch (512 blocks = 2/CU, the
    //      co-residency today's LDS footprint already achieves)
    int coop_blocks = 512;
    {
        void* args[] = {
            (void*)&data, (void*)&weights, (void*)&neigh, (void*)&batch_id,
            (void*)&gamma, (void*)&beta,
            (void*)&dpk, (void*)&wpk, (void*)&hraw, (void*)&hok,
            (void*)&out, (void*)&gs1, (void*)&gs2, (void*)&gcnt, (void*)&N
        };
        hipError_t e = hipLaunchCooperativeKernel(
            (const void*)fused_all_kernel, dim3(coop_blocks), dim3(256),
            args, 0, stream);
        if (e == hipSuccess) return;
        (void)hipGetLastError();   // clear sticky error, fall through
    }

    // ---- fallback: proven 3-dispatch path (round-4, 260 us)
    const int nbData = (N * 8 + 255) / 256;
    hipLaunchKernelGGL(pack_all_kernel, dim3(nbData + 15), dim3(256),
                       0, stream, data, dpk, weights, wpk, gs1, N, nbData);

    const int nblocks = (N + 127) / 128;
    hipLaunchKernelGGL(deconv_stats_kernel, dim3(nblocks), dim3(256), 0, stream,
                       dpk, wpk, neigh, batch_id, out,
                       hraw, hok, gs1, gs2, gcnt, N);

    const int n8 = N * 8;
    hipLaunchKernelGGL(gn_relu_kernel, dim3((n8 + 255) / 256), dim3(256), 0,
                       stream, out, hraw, hok, batch_id,
                       gs1, gs2, gcnt, gamma, beta, N);
}

// Round 6
// 258.989 us; speedup vs baseline: 1.8615x; 1.8615x over previous
//
#include <hip/hip_runtime.h>
#include <math.h>

#define EPS 1e-5f

typedef __attribute__((ext_vector_type(8)))  _Float16 half8;   // 8 f16 (4 VGPR)
typedef __attribute__((ext_vector_type(16))) float    floatx16;

__device__ __forceinline__ unsigned short f2h_bits(float f) {
    _Float16 h = (_Float16)f;
    return __builtin_bit_cast(unsigned short, h);
}

// ---------------------------------------------------------------------------
// Fused prepass: one dispatch, block-range dispatch to roles.
//   blocks [0, nbData)       : data[N][32] fp32 -> dpk[N][32] f16
//   blocks [nbData, nbData+14): W[27][32][32] -> f16 B-fragments (wpk)
//   block   nbData+14        : zero gs1/gs2/gcnt (520 floats)
// ---------------------------------------------------------------------------
__global__ __launch_bounds__(256) void pack_all_kernel(
    const float* __restrict__ data, unsigned short* __restrict__ dpk,
    const float* __restrict__ W, unsigned short* __restrict__ wpk,
    float* __restrict__ gzero, int N, int nbData)
{
    const int b = blockIdx.x;
    const int tid = threadIdx.x;

    if (b < nbData) {
        const int i = b * 256 + tid;                 // float4 index
        if (i >= N * 8) return;
        const float4 v = ((const float4*)data)[i];
        ushort4 o;
        o.x = f2h_bits(v.x);
        o.y = f2h_bits(v.y);
        o.z = f2h_bits(v.z);
        o.w = f2h_bits(v.w);
        ((ushort4*)dpk)[i] = o;
        return;
    }
    const int wb = b - nbData;
    if (wb < 14) {
        // B[k][n]: lane l holds n=l&31, k=8*(l>>5)+j. Tap 27 = zeros.
        const int t = wb * 256 + tid;                // (tap*2+chunk)*64+lane
        const int l = t & 63;
        const int c = (t >> 6) & 1;
        const int k = t >> 7;
        ushort4 o0 = make_ushort4(0, 0, 0, 0), o1 = o0;
        if (k < 27) {
            const int n  = l & 31;
            const int cb = c * 16 + (l >> 5) * 8;    // ci base for this lane
            const float* wp = W + k * 1024 + n;
            o0.x = f2h_bits(wp[(cb + 0) * 32]);
            o0.y = f2h_bits(wp[(cb + 1) * 32]);
            o0.z = f2h_bits(wp[(cb + 2) * 32]);
            o0.w = f2h_bits(wp[(cb + 3) * 32]);
            o1.x = f2h_bits(wp[(cb + 4) * 32]);
            o1.y = f2h_bits(wp[(cb + 5) * 32]);
            o1.z = f2h_bits(wp[(cb + 6) * 32]);
            o1.w = f2h_bits(wp[(cb + 7) * 32]);
        }
        *(ushort4*)(wpk + (size_t)t * 8)     = o0;
        *(ushort4*)(wpk + (size_t)t * 8 + 4) = o1;
        return;
    }
    if (wb == 14) {
        if (tid < 520) gzero[tid] = 0.f;             // zero global stats
        return;
    }
}

// ---------------------------------------------------------------------------
// Deconv via f16 MFMA + GN stats. Round-0 proven structure + round-3 f16 hraw
// + round-4 direct neigh reads. ROUND-6: exact revert to the round-4 best
// (260.2 us) after the persistent-fusion experiment regressed (r5: phase-1
// throughput halved -- persistent chunk loops drain the gather pipeline at
// chunk boundaries; short independent blocks ARE the pipeline).
// Evidence r0-r1: occupancy 20->40% null at ~3.5-3.8 TB/s => random-64B
// fabric wall; deconv runs within ~5% of 518 MB irreducible demand / wall.
// Block = 256 = 4 waves; wave = 32 nodes x 32 couts; B staged in LDS (57 KB).
// ---------------------------------------------------------------------------
__global__ __launch_bounds__(256) void deconv_stats_kernel(
    const unsigned short* __restrict__ dpk, const unsigned short* __restrict__ wpk,
    const int* __restrict__ neigh,
    const int* __restrict__ batch_id, float* __restrict__ out,
    unsigned short* __restrict__ hraw, int hok,
    float* __restrict__ gs1, float* __restrict__ gs2, float* __restrict__ gcnt,
    int N)
{
    __shared__ unsigned short BW[28 * 2 * 64 * 8];    // 57344 B
    __shared__ float ls1[256];
    __shared__ float ls2[256];
    __shared__ float lcnt[8];

    const int t    = threadIdx.x;
    const int wv   = t >> 6;
    const int l    = t & 63;
    const int mrow = l & 31;
    const int half = l >> 5;
    const int wbase = blockIdx.x * 128 + wv * 32;
    const int node  = wbase + mrow;
    const int nc    = node < N ? node : N - 1;

    // stage all B fragments to LDS (coalesced, 14 x 4 KB)
#pragma unroll
    for (int r = 0; r < 14; ++r)
        ((int4*)BW)[r * 256 + t] = ((const int4*)wpk)[r * 256 + t];
    ls1[t] = 0.f;
    ls2[t] = 0.f;
    if (t < 8) lcnt[t] = 0.f;
    __syncthreads();

    floatx16 acc;
#pragma unroll
    for (int r = 0; r < 16; ++r) acc[r] = 0.f;

    const int* nrow = neigh + (size_t)nc * 27;
    const int aoff  = half * 8;      // f16 offset: chunk c base = 16c + 8*half

    int4 nq;
    nq.x = nrow[0]; nq.y = nrow[1]; nq.z = nrow[2]; nq.w = nrow[3];

    half8 a0, a1, a2, a3, a4, a5, a6, a7;     // current quad: tap j, chunk c -> a(2j+c)
    {
        const unsigned short* r0 = dpk + (size_t)nq.x * 32;
        const unsigned short* r1 = dpk + (size_t)nq.y * 32;
        const unsigned short* r2 = dpk + (size_t)nq.z * 32;
        const unsigned short* r3 = dpk + (size_t)nq.w * 32;
        a0 = *(const half8*)(r0 + aoff);  a1 = *(const half8*)(r0 + 16 + aoff);
        a2 = *(const half8*)(r1 + aoff);  a3 = *(const half8*)(r1 + 16 + aoff);
        a4 = *(const half8*)(r2 + aoff);  a5 = *(const half8*)(r2 + 16 + aoff);
        a6 = *(const half8*)(r3 + aoff);  a7 = *(const half8*)(r3 + 16 + aoff);
    }

    const half8* BL = (const half8*)BW;

#pragma unroll 1
    for (int it = 0; it < 7; ++it) {
        half8 b0, b1, b2, b3, b4, b5, b6, b7;
        if (it < 6) {                 // issue next quad's gathers (latency cover)
            const int kb = (it + 1) * 4;
            int4 nqn;
            nqn.x = nrow[kb];
            nqn.y = nrow[kb + 1];
            nqn.z = nrow[kb + 2];
            nqn.w = nrow[kb + 3 < 27 ? kb + 3 : 26];
            const unsigned short* r0 = dpk + (size_t)nqn.x * 32;
            const unsigned short* r1 = dpk + (size_t)nqn.y * 32;
            const unsigned short* r2 = dpk + (size_t)nqn.z * 32;
            const unsigned short* r3 = dpk + (size_t)nqn.w * 32;
            b0 = *(const half8*)(r0 + aoff);  b1 = *(const half8*)(r0 + 16 + aoff);
            b2 = *(const half8*)(r1 + aoff);  b3 = *(const half8*)(r1 + 16 + aoff);
            b4 = *(const half8*)(r2 + aoff);  b5 = *(const half8*)(r2 + 16 + aoff);
            b6 = *(const half8*)(r3 + aoff);  b7 = *(const half8*)(r3 + 16 + aoff);
        }

        // compute current quad: (tap*2+chunk) = 8*it + (0..7) matches a0..a7
        acc = __builtin_amdgcn_mfma_f32_32x32x16_f16(a0, BL[(8 * it + 0) * 64 + l], acc, 0, 0, 0);
        acc = __builtin_amdgcn_mfma_f32_32x32x16_f16(a1, BL[(8 * it + 1) * 64 + l], acc, 0, 0, 0);
        acc = __builtin_amdgcn_mfma_f32_32x32x16_f16(a2, BL[(8 * it + 2) * 64 + l], acc, 0, 0, 0);
        acc = __builtin_amdgcn_mfma_f32_32x32x16_f16(a3, BL[(8 * it + 3) * 64 + l], acc, 0, 0, 0);
        acc = __builtin_amdgcn_mfma_f32_32x32x16_f16(a4, BL[(8 * it + 4) * 64 + l], acc, 0, 0, 0);
        acc = __builtin_amdgcn_mfma_f32_32x32x16_f16(a5, BL[(8 * it + 5) * 64 + l], acc, 0, 0, 0);
        acc = __builtin_amdgcn_mfma_f32_32x32x16_f16(a6, BL[(8 * it + 6) * 64 + l], acc, 0, 0, 0);
        acc = __builtin_amdgcn_mfma_f32_32x32x16_f16(a7, BL[(8 * it + 7) * 64 + l], acc, 0, 0, 0);

        if (it < 6) {
            a0 = b0; a1 = b1; a2 = b2; a3 = b3;
            a4 = b4; a5 = b5; a6 = b6; a7 = b7;
        }
    }

    // ---- epilogue (proven): C layout col=l&31, row=(r&3)+8(r>>2)+4*half
    // Pre-GN activations stored as f16 (hraw) when workspace allows: halves
    // the write traffic and the L2 pollution; f32 fallback otherwise.
    const int co = mrow;
    if (hok) {
#pragma unroll
        for (int r = 0; r < 16; ++r) {
            const int row = (r & 3) + 8 * (r >> 2) + 4 * half;
            const int n = wbase + row;
            if (n < N) hraw[(size_t)n * 32 + co] = f2h_bits(acc[r]);
        }
    } else {
#pragma unroll
        for (int r = 0; r < 16; ++r) {
            const int row = (r & 3) + 8 * (r >> 2) + 4 * half;
            const int n = wbase + row;
            if (n < N) out[(size_t)n * 32 + co] = acc[r];
        }
    }

    bool fast = (wbase + 31 < N);
    int bfst = 0;
    if (fast) {
        bfst = batch_id[wbase];
        fast = (bfst == batch_id[wbase + 31]);
    }
    if (fast) {
        float s1 = 0.f, s2 = 0.f;
#pragma unroll
        for (int r = 0; r < 16; ++r) {
            const float v = acc[r];
            s1 += v;
            s2 += v * v;
        }
        atomicAdd(&ls1[bfst * 32 + co], s1);
        atomicAdd(&ls2[bfst * 32 + co], s2);
    } else {
#pragma unroll
        for (int r = 0; r < 16; ++r) {
            const int row = (r & 3) + 8 * (r >> 2) + 4 * half;
            const int n = wbase + row;
            if (n < N) {
                const int b = batch_id[n];
                const float v = acc[r];
                atomicAdd(&ls1[b * 32 + co], v);
                atomicAdd(&ls2[b * 32 + co], v * v);
            }
        }
    }
    if (half == 0) {
        const int n = wbase + mrow;
        if (n < N) atomicAdd(&lcnt[batch_id[n]], 1.0f);
    }
    __syncthreads();

    {
        float v;
        v = ls1[t]; if (v != 0.f) atomicAdd(&gs1[t], v);
        v = ls2[t]; if (v != 0.f) atomicAdd(&gs2[t], v);
        if (t < 8) { v = lcnt[t]; if (v != 0.f) atomicAdd(&gcnt[t], v); }
    }
}

// ---------------------------------------------------------------------------
// GN finalize + apply + ReLU. Reads f16 hraw when available (halved input
// traffic), writes f32 out once.
// ---------------------------------------------------------------------------
__global__ __launch_bounds__(256) void gn_relu_kernel(
    float* __restrict__ out, const unsigned short* __restrict__ hraw, int hok,
    const int* __restrict__ batch_id,
    const float* __restrict__ gs1, const float* __restrict__ gs2,
    const float* __restrict__ gcnt, const float* __restrict__ gamma,
    const float* __restrict__ beta, int N)
{
    const int idx = blockIdx.x * 256 + threadIdx.x;
    if (idx >= N * 8) return;
    const int n = idx >> 3;
    const int g = idx & 7;
    const int b = batch_id[n];

    const float cnt  = gcnt[b] * 4.0f;
    const float icnt = 1.0f / (cnt + EPS);
    const float4 s1 = *(const float4*)(gs1 + b * 32 + g * 4);
    const float4 s2 = *(const float4*)(gs2 + b * 32 + g * 4);
    const float S1 = s1.x + s1.y + s1.z + s1.w;
    const float S2 = s2.x + s2.y + s2.z + s2.w;
    const float m   = S1 * icnt;
    const float var = (S2 - 2.0f * m * S1 + cnt * m * m) * icnt;
    const float istd = rsqrtf(var + EPS);

    const float4 gm4 = *(const float4*)(gamma + g * 4);
    const float4 bt4 = *(const float4*)(beta + g * 4);
    float4 h;
    if (hok) {
        const ushort4 hv = *(const ushort4*)(hraw + (size_t)idx * 4);
        h.x = (float)__builtin_bit_cast(_Float16, hv.x);
        h.y = (float)__builtin_bit_cast(_Float16, hv.y);
        h.z = (float)__builtin_bit_cast(_Float16, hv.z);
        h.w = (float)__builtin_bit_cast(_Float16, hv.w);
    } else {
        h = *(float4*)(out + (size_t)idx * 4);
    }
    h.x = fmaxf((h.x - m) * istd * gm4.x + bt4.x, 0.f);
    h.y = fmaxf((h.y - m) * istd * gm4.y + bt4.y, 0.f);
    h.z = fmaxf((h.z - m) * istd * gm4.z + bt4.z, 0.f);
    h.w = fmaxf((h.w - m) * istd * gm4.w + bt4.w, 0.f);
    *(float4*)(out + (size_t)idx * 4) = h;
}

// ---------------------------------------------------------------------------
extern "C" void kernel_launch(void* const* d_in, const int* in_sizes, int n_in,
                              void* d_out, int out_size, void* d_ws, size_t ws_size,
                              hipStream_t stream) {
    const float* data     = (const float*)d_in[0];   // [N,32]
    const float* weights  = (const float*)d_in[1];   // [27,32,32]
    const float* gamma    = (const float*)d_in[2];   // [32]
    const float* beta     = (const float*)d_in[3];   // [32]
    const int*   neigh    = (const int*)d_in[4];     // [N,27]
    const int*   batch_id = (const int*)d_in[5];     // [N]
    const int N = in_sizes[0] / 32;
    float* out = (float*)d_out;

    // ws layout (bytes):
    //   [0, 2080)                 : gs1[256] gs2[256] gcnt[8]
    //   [4096, +N*64)             : dpk   (N x 32 f16)
    //   [.., +57344)              : wpk   (28*2*64 half8 fragments)
    //   [.., +N*64)               : hraw  (N x 32 f16)    -- if ws fits
    char* wsb = (char*)d_ws;
    float* gs1  = (float*)wsb;
    float* gs2  = gs1 + 256;
    float* gcnt = gs1 + 512;
    unsigned short* dpk = (unsigned short*)(wsb + 4096);
    unsigned short* wpk = (unsigned short*)(wsb + 4096 + (size_t)N * 64);
    unsigned short* hraw = (unsigned short*)(wsb + 4096 + (size_t)N * 64 + 57344);

    const size_t need_hr = 4096 + (size_t)N * 64 + 57344 + (size_t)N * 64;
    const int hraw_ok = (ws_size >= need_hr) ? 1 : 0;

    // fused prepass: data pack + w pack + gs zero
    const int nbData = (N * 8 + 255) / 256;
    hipLaunchKernelGGL(pack_all_kernel, dim3(nbData + 15), dim3(256),
                       0, stream, data, dpk, weights, wpk, gs1, N, nbData);

    const int nblocks = (N + 127) / 128;
    hipLaunchKernelGGL(deconv_stats_kernel, dim3(nblocks), dim3(256), 0, stream,
                       dpk, wpk, neigh, batch_id, out,
                       hraw, hraw_ok, gs1, gs2, gcnt, N);

    const int n8 = N * 8;
    hipLaunchKernelGGL(gn_relu_kernel, dim3((n8 + 255) / 256), dim3(256), 0,
                       stream, out, hraw, hraw_ok, batch_id,
                       gs1, gs2, gcnt, gamma, beta, N);
}